// Round 4
// baseline (1250.310 us; speedup 1.0000x reference)
//
#include <hip/hip_runtime.h>
#include <hip/hip_bf16.h>
#include <math.h>

#define NN 100000
#define NE 1600000
#define FF 64
#define NB 64
#define NSCAN_BLOCKS 391   // ceil(NN/256)

// avg_deg['log'] = sum(log(i+1)*DEG[i]) / sum(DEG)
__device__ __constant__ float AVG_LOG_F = 1.9595436f;

typedef short short8 __attribute__((ext_vector_type(8)));
typedef float f32x4 __attribute__((ext_vector_type(4)));

__device__ __forceinline__ void atomAddF(float* p, float v) {
    __hip_atomic_fetch_add(p, v, __ATOMIC_RELAXED, __HIP_MEMORY_SCOPE_AGENT);
}

// ---------------- fold weights: Wtb = (Wo@Wl)^T in bf16, We'=We@Wp2, biases ----------------
__global__ void fold_weights(const float* __restrict__ Wo, const float* __restrict__ Wl,
                             const float* __restrict__ bo, const float* __restrict__ bl,
                             const float* __restrict__ We, const float* __restrict__ Wp,
                             const float* __restrict__ bp, const float* __restrict__ be,
                             __hip_bfloat16* __restrict__ Wtb,   // [64][832]  Wtb[f][k] = (Wo@Wl)[k][f]
                             float* __restrict__ Wep,  // [16][64]
                             float* __restrict__ bpF, float* __restrict__ boF) {
    int t = blockIdx.x * blockDim.x + threadIdx.x;
    if (t < 832 * 64) {
        int k = t >> 6, f = t & 63;
        float acc = 0.f;
        for (int j = 0; j < 64; j++) acc += Wo[k * 64 + j] * Wl[j * 64 + f];
        Wtb[f * 832 + k] = __float2bfloat16(acc);
    } else if (t < 832 * 64 + 16 * 64) {
        int u = t - 832 * 64; int k = u >> 6, f = u & 63;
        float acc = 0.f;
        for (int j = 0; j < 64; j++) acc += We[k * 64 + j] * Wp[(128 + j) * 64 + f];
        Wep[k * 64 + f] = acc;
    } else if (t < 832 * 64 + 1024 + 64) {
        int f = t - (832 * 64 + 1024);
        float acc = bl[f];
        for (int j = 0; j < 64; j++) acc += bo[j] * Wl[j * 64 + f];
        boF[f] = acc;
    } else if (t < 832 * 64 + 1024 + 128) {
        int f = t - (832 * 64 + 1024 + 64);
        float acc = bp[f];
        for (int j = 0; j < 64; j++) acc += be[j] * Wp[(128 + j) * 64 + f];
        bpF[f] = acc;
    }
}

// ---------------- node pre-MLP + A/B projections (wave per node) ----------------
__global__ __launch_bounds__(256) void node_pre(const float* __restrict__ x,
                                                const float* __restrict__ W1, const float* __restrict__ b1,
                                                const float* __restrict__ W2, const float* __restrict__ b2,
                                                const float* __restrict__ Wp,
                                                float* __restrict__ x2, float* __restrict__ A, float* __restrict__ Bn) {
    __shared__ float W1s[64 * 32], W2s[32 * 64], Wp0s[64 * 64], Wp1s[64 * 64];
    __shared__ float xs[4][64], ts[4][32], x2s[4][64];
    int tid = threadIdx.x;
    for (int i = tid; i < 2048; i += 256) W1s[i] = W1[i];
    for (int i = tid; i < 2048; i += 256) W2s[i] = W2[i];
    for (int i = tid; i < 4096; i += 256) Wp0s[i] = Wp[i];
    for (int i = tid; i < 4096; i += 256) Wp1s[i] = Wp[4096 + i];
    __syncthreads();
    int w = tid >> 6, f = tid & 63;
    int wid = blockIdx.x * 4 + w;
    int nw = gridDim.x * 4;
    for (int v = wid; v < NN; v += nw) {
        xs[w][f] = x[(size_t)v * 64 + f];
        if (f < 32) {
            float tj = b1[f];
            for (int k = 0; k < 64; k++) tj += xs[w][k] * W1s[k * 32 + f];
            ts[w][f] = fmaxf(tj, 0.f);
        }
        float acc2 = b2[f];
        for (int k = 0; k < 32; k++) acc2 += ts[w][k] * W2s[k * 64 + f];
        x2s[w][f] = acc2;
        x2[(size_t)v * 64 + f] = acc2;
        float aa = 0.f, bb = 0.f;
        for (int k = 0; k < 64; k++) {
            float xv = x2s[w][k];
            aa += xv * Wp0s[k * 64 + f];
            bb += xv * Wp1s[k * 64 + f];
        }
        A[(size_t)v * 64 + f] = aa;
        Bn[(size_t)v * 64 + f] = bb;
    }
}

// ---------------- counting sort of edges by dst ----------------
__global__ void hist_kernel(const int* __restrict__ ei, unsigned* __restrict__ cnt_i) {
    int t = blockIdx.x * blockDim.x + threadIdx.x;
    if (t < NE) atomicAdd(&cnt_i[ei[NE + t]], 1u);
}

__global__ void scan_blocksum(const unsigned* __restrict__ cnt_i, unsigned* __restrict__ bsum) {
    __shared__ unsigned red[256];
    int t = blockIdx.x * 256 + threadIdx.x;
    unsigned c = (t < NN) ? cnt_i[t] : 0u;
    red[threadIdx.x] = c; __syncthreads();
    for (int s = 128; s > 0; s >>= 1) {
        if (threadIdx.x < s) red[threadIdx.x] += red[threadIdx.x + s];
        __syncthreads();
    }
    if (threadIdx.x == 0) bsum[blockIdx.x] = red[0];
}

__global__ void scan_top(const unsigned* __restrict__ bsum, unsigned* __restrict__ boff,
                         unsigned* __restrict__ start) {
    __shared__ unsigned sh[512];
    int t = threadIdx.x;
    unsigned v = (t < NSCAN_BLOCKS) ? bsum[t] : 0u;
    sh[t] = v; __syncthreads();
    for (int d = 1; d < 512; d <<= 1) {
        unsigned add = (t >= d) ? sh[t - d] : 0u;
        __syncthreads();
        sh[t] += add;
        __syncthreads();
    }
    if (t < NSCAN_BLOCKS) boff[t] = sh[t] - v;   // exclusive
    if (t == 0) start[NN] = NE;
}

__global__ void scan_final(const unsigned* __restrict__ cnt_i, const unsigned* __restrict__ boff,
                           unsigned* __restrict__ start) {
    __shared__ unsigned sh[256];
    int b = blockIdx.x, t = threadIdx.x;
    int v = b * 256 + t;
    unsigned c = (v < NN) ? cnt_i[v] : 0u;
    sh[t] = c; __syncthreads();
    for (int d = 1; d < 256; d <<= 1) {
        unsigned add = (t >= d) ? sh[t - d] : 0u;
        __syncthreads();
        sh[t] += add;
        __syncthreads();
    }
    if (v < NN) start[v] = boff[b] + sh[t] - c;  // exclusive scan
}

__global__ void scatter_kernel(const int* __restrict__ ei, const unsigned* __restrict__ start,
                               unsigned* __restrict__ cnt_i, unsigned* __restrict__ perm) {
    int t = blockIdx.x * blockDim.x + threadIdx.x;
    if (t < NE) {
        int d = ei[NE + t];
        unsigned old = atomicSub(&cnt_i[d], 1u);
        perm[start[d] + old - 1u] = (unsigned)t;
    }
}

// ---------------- per-node segment aggregation (wave per node, 3-deep SW pipeline) ----------------
// Chain per edge is perm[j] -> ei/ea[e] -> Bn[src]; stages are rotated so each
// load has ~3 iterations of slack. Prefetch indices are clamped to the segment
// (duplicate loads, never OOB, never used by compute).
__global__ __launch_bounds__(256) void agg_kernel(const float* __restrict__ ea, const int* __restrict__ ei,
                                                  const unsigned* __restrict__ perm, const unsigned* __restrict__ start,
                                                  const float* __restrict__ A, const float* __restrict__ Bn,
                                                  const float* __restrict__ Wep, const float* __restrict__ bpF,
                                                  float* __restrict__ meanO, float* __restrict__ mnO,
                                                  float* __restrict__ mxO, float* __restrict__ sdO,
                                                  float* __restrict__ cntO) {
    int tid = threadIdx.x, w = tid >> 6, f = tid & 63;
    float wcol[16];
    #pragma unroll
    for (int k = 0; k < 16; k++) wcol[k] = Wep[k * 64 + f];
    float bpf = bpF[f];
    int wid = blockIdx.x * 4 + w;
    int nw = gridDim.x * 4;
    for (int v = wid; v < NN; v += nw) {
        unsigned s0 = start[v], s1 = start[v + 1];
        int len = (int)(s1 - s0);
        float av = A[(size_t)v * 64 + f] + bpf;
        float s = 0.f, s2 = 0.f, mn = INFINITY, mx = -INFINITY;
        if (len > 0) {
            unsigned last = s1 - 1;
            // prologue: fill stages for j, j+1, j+2 (clamped)
            unsigned e0 = perm[s0];
            unsigned i1 = s0 + 1 > last ? last : s0 + 1;
            unsigned i2 = s0 + 2 > last ? last : s0 + 2;
            unsigned e1 = perm[i1];
            unsigned eA = perm[i2];
            int src0 = ei[e0];
            int srcB = ei[e1];
            const float4* p0 = (const float4*)(ea + (size_t)e0 * 16);
            float4 c0 = p0[0], c1 = p0[1], c2 = p0[2], c3 = p0[3];
            const float4* p1 = (const float4*)(ea + (size_t)e1 * 16);
            float4 b0 = p1[0], b1 = p1[1], b2 = p1[2], b3 = p1[3];
            float bnC = Bn[(size_t)src0 * 64 + f];
            for (unsigned j = s0; j < s1; ++j) {
                // stage-3: perm for j+3
                unsigned j3 = j + 3 > last ? last : j + 3;
                unsigned eN = perm[j3];
                // stage-2: ei/ea for j+2
                int srcN = ei[eA];
                const float4* pN = (const float4*)(ea + (size_t)eA * 16);
                float4 n0 = pN[0], n1 = pN[1], n2 = pN[2], n3 = pN[3];
                // stage-1: Bn for j+1
                float bnN = Bn[(size_t)srcB * 64 + f];
                // compute j
                float h = av + bnC;
                h += c0.x * wcol[0] + c0.y * wcol[1] + c0.z * wcol[2] + c0.w * wcol[3];
                h += c1.x * wcol[4] + c1.y * wcol[5] + c1.z * wcol[6] + c1.w * wcol[7];
                h += c2.x * wcol[8] + c2.y * wcol[9] + c2.z * wcol[10] + c2.w * wcol[11];
                h += c3.x * wcol[12] + c3.y * wcol[13] + c3.z * wcol[14] + c3.w * wcol[15];
                s += h; s2 += h * h;
                mn = fminf(mn, h); mx = fmaxf(mx, h);
                // rotate
                c0 = b0; c1 = b1; c2 = b2; c3 = b3; bnC = bnN;
                b0 = n0; b1 = n1; b2 = n2; b3 = n3; srcB = srcN; eA = eN;
            }
        }
        float c = (float)len;
        float d = fmaxf(c, 1.f);
        float inv = 1.f / d;
        float mean = s * inv, mean2 = s2 * inv;
        float sd = sqrtf(fmaxf(mean2 - mean * mean, 0.f) + 1e-5f);
        bool has = len > 0;
        size_t o = (size_t)v * 64 + f;
        meanO[o] = mean;
        mnO[o] = has ? mn : 0.f;
        mxO[o] = has ? mx : 0.f;
        sdO[o] = sd;
        if (f == 0) cntO[v] = c;
    }
}

// ---------------- post GEMM via MFMA: out_pre = cs[832] @ (Wo@Wl) + bo', fused BN-stats ----------------
__global__ __launch_bounds__(256) void post_kernel(const float* __restrict__ x2,
                                                   const float* __restrict__ meanI, const float* __restrict__ mnI,
                                                   const float* __restrict__ mxI, const float* __restrict__ sdI,
                                                   const float* __restrict__ cnt,
                                                   const __hip_bfloat16* __restrict__ Wtb, const float* __restrict__ boF,
                                                   float* __restrict__ out_pre,
                                                   float* __restrict__ bnsum, float* __restrict__ bnsum2) {
    __shared__ __hip_bfloat16 As[16 * 840];
    int tid = threadIdx.x, w = tid >> 6, f = tid & 63;
    int base = blockIdx.x * 16;      // 100000/16 = 6250 blocks exactly

    // phase A: build scaled feature vectors (bf16)
    for (int g = 0; g < 4; ++g) {
        int n = g * 4 + w;
        int v = base + n;
        size_t o = (size_t)v * 64 + f;
        float c = cnt[v];
        float d = fmaxf(c, 1.f);
        float mean = meanI[o];
        float sd = sdI[o];
        float mn = mnI[o];
        float mx = mxI[o];
        float l = __logf(d + 1.f);
        float amp = l * (1.0f / 1.9595436f);
        float iamp = 1.9595436f * __builtin_amdgcn_rcpf(l);
        __hip_bfloat16* row = &As[n * 840];
        row[f]        = __float2bfloat16(x2[o]);
        row[64 + f]   = __float2bfloat16(mean);
        row[128 + f]  = __float2bfloat16(mn);
        row[192 + f]  = __float2bfloat16(mx);
        row[256 + f]  = __float2bfloat16(sd);
        row[320 + f]  = __float2bfloat16(mean * amp);
        row[384 + f]  = __float2bfloat16(mn * amp);
        row[448 + f]  = __float2bfloat16(mx * amp);
        row[512 + f]  = __float2bfloat16(sd * amp);
        row[576 + f]  = __float2bfloat16(mean * iamp);
        row[640 + f]  = __float2bfloat16(mn * iamp);
        row[704 + f]  = __float2bfloat16(mx * iamp);
        row[768 + f]  = __float2bfloat16(sd * iamp);
    }
    __syncthreads();

    // phase B: MFMA. lane = m + 16q; A[m][k=q*8+j], B[k=q*8+j][n=m], D: col=lane&15, row=q*4+reg
    int m = f & 15, q = f >> 4;
    int fbase = w * 16;
    f32x4 acc = {0.f, 0.f, 0.f, 0.f};
    const __hip_bfloat16* arow = &As[m * 840 + q * 8];
    const __hip_bfloat16* brow = &Wtb[(size_t)(fbase + m) * 832 + q * 8];
    #pragma unroll
    for (int s = 0; s < 26; ++s) {
        short8 af = *(const short8*)(arow + s * 32);
        short8 bf = *(const short8*)(brow + s * 32);
        acc = __builtin_amdgcn_mfma_f32_16x16x32_bf16(af, bf, acc, 0, 0, 0);
    }

    float bof = boF[fbase + m];
    float p1 = 0.f, p2 = 0.f;
    #pragma unroll
    for (int r = 0; r < 4; ++r) {
        float vv = acc[r] + bof;
        out_pre[(size_t)(base + q * 4 + r) * 64 + fbase + m] = vv;
        p1 += vv; p2 += vv * vv;
    }
    // reduce across the 4 quads (same feature col)
    p1 += __shfl_xor(p1, 16); p2 += __shfl_xor(p2, 16);
    p1 += __shfl_xor(p1, 32); p2 += __shfl_xor(p2, 32);
    if (f < 16) {
        atomAddF(&bnsum[fbase + f], p1);
        atomAddF(&bnsum2[fbase + f], p2);
    }
}

// ---------------- BN finalize ----------------
__global__ void bn_finalize(const float* __restrict__ bnsum, const float* __restrict__ bnsum2,
                            const float* __restrict__ gamma, const float* __restrict__ beta,
                            float* __restrict__ bnscale, float* __restrict__ bnshift) {
    int f = threadIdx.x;
    if (f < 64) {
        float mu = bnsum[f] * (1.0f / NN);
        float var = bnsum2[f] * (1.0f / NN) - mu * mu;
        float sc = gamma[f] / sqrtf(var + 1e-5f);
        bnscale[f] = sc;
        bnshift[f] = beta[f] - mu * sc;
    }
}

// ---------------- BN apply + ReLU + global_add_pool ----------------
__global__ __launch_bounds__(256) void bn_pool(const float* __restrict__ out_pre, const int* __restrict__ batch,
                                               const float* __restrict__ bnscale, const float* __restrict__ bnshift,
                                               float* __restrict__ pooled) {
    __shared__ float red[256];
    int tid = threadIdx.x, f = tid & 63, q = tid >> 6;
    int base = blockIdx.x * 64;
    float sc = bnscale[f], sh = bnshift[f];
    int b_first = batch[base < NN ? base : NN - 1];
    int last = base + 63; if (last >= NN) last = NN - 1;
    int b_last = batch[last];
    if (b_first == b_last) {
        float local = 0.f;
        for (int g = 0; g < 16; ++g) {
            int v = base + g * 4 + q;
            if (v < NN) local += fmaxf(out_pre[(size_t)v * 64 + f] * sc + sh, 0.f);
        }
        red[tid] = local;
        __syncthreads();
        if (tid < 64) atomAddF(&pooled[b_first * 64 + f], red[f] + red[f + 64] + red[f + 128] + red[f + 192]);
    } else {
        for (int g = 0; g < 16; ++g) {
            int v = base + g * 4 + q;
            if (v < NN) {
                float val = fmaxf(out_pre[(size_t)v * 64 + f] * sc + sh, 0.f);
                atomAddF(&pooled[batch[v] * 64 + f], val);
            }
        }
    }
}

// ---------------- head MLP: relu(pooled@Wm1+bm1)@Wm2+bm2 ----------------
__global__ void head_kernel(const float* __restrict__ pooled,
                            const float* __restrict__ Wm1, const float* __restrict__ bm1,
                            const float* __restrict__ Wm2, const float* __restrict__ bm2,
                            float* __restrict__ out) {
    __shared__ float ts[64][104];
    int tid = threadIdx.x;
    for (int t = tid; t < 64 * 100; t += 256) {
        int b = t / 100, j = t % 100;
        float acc = bm1[j];
        for (int k = 0; k < 64; k++) acc += pooled[b * 64 + k] * Wm1[k * 100 + j];
        ts[b][j] = fmaxf(acc, 0.f);
    }
    __syncthreads();
    if (tid < 64) {
        float acc = bm2[0];
        for (int j = 0; j < 100; j++) acc += ts[tid][j] * Wm2[j];
        out[tid] = acc;
    }
}

extern "C" void kernel_launch(void* const* d_in, const int* in_sizes, int n_in,
                              void* d_out, int out_size, void* d_ws, size_t ws_size,
                              hipStream_t stream) {
    const float* x    = (const float*)d_in[0];
    const float* ea   = (const float*)d_in[1];
    const int*   ei   = (const int*)d_in[2];
    const int*   batch= (const int*)d_in[3];
    const float* W1   = (const float*)d_in[4];
    const float* b1   = (const float*)d_in[5];
    const float* W2   = (const float*)d_in[6];
    const float* b2   = (const float*)d_in[7];
    const float* We   = (const float*)d_in[8];
    const float* be   = (const float*)d_in[9];
    const float* Wp   = (const float*)d_in[10];
    const float* bp   = (const float*)d_in[11];
    const float* Wo   = (const float*)d_in[12];
    const float* bo   = (const float*)d_in[13];
    const float* Wl   = (const float*)d_in[14];
    const float* bl   = (const float*)d_in[15];
    const float* gamma= (const float*)d_in[16];
    const float* beta = (const float*)d_in[17];
    const float* Wm1  = (const float*)d_in[18];
    const float* bm1  = (const float*)d_in[19];
    const float* Wm2  = (const float*)d_in[20];
    const float* bm2  = (const float*)d_in[21];

    float* ws = (float*)d_ws;
    constexpr size_t NF = (size_t)NN * 64;              // 6,400,000
    const size_t o_x2     = 0;
    const size_t o_B      = NF;
    const size_t o_A      = 2 * NF;                     // reused as out_pre after agg_kernel
    const size_t o_mean   = 3 * NF;
    const size_t o_mn     = 4 * NF;
    const size_t o_mx     = 5 * NF;
    const size_t o_sd     = 6 * NF;
    const size_t o_cntf   = 7 * NF;
    const size_t o_start  = o_cntf + NN;                // NN+1 uints
    const size_t o_cnt_i  = o_start + NN + 2;           // NN uints (memset 0)
    const size_t o_bsum   = o_cnt_i + NN;
    const size_t o_boff   = o_bsum + 512;
    const size_t o_perm   = o_boff + 512;               // NE uints
    const size_t o_Wtb    = o_perm + NE;                // 64*832 bf16 = 26624 float slots
    const size_t o_Wep    = o_Wtb + 64 * 832 / 2;
    const size_t o_bpF    = o_Wep + 16 * 64;
    const size_t o_boF    = o_bpF + 64;
    const size_t o_bnscale= o_boF + 64;
    const size_t o_bnshift= o_bnscale + 64;
    const size_t o_pooled = o_bnshift + 64;             // zero block: pooled + bnsum + bnsum2
    const size_t o_bnsum  = o_pooled + 64 * 64;
    const size_t o_bnsum2 = o_bnsum + 64;

    // zero the histogram and the small accumulators
    hipMemsetAsync(ws + o_cnt_i, 0, NN * sizeof(unsigned), stream);
    hipMemsetAsync(ws + o_pooled, 0, (64 * 64 + 128) * sizeof(float), stream);

    fold_weights<<<213, 256, 0, stream>>>(Wo, Wl, bo, bl, We, Wp, bp, be,
                                          (__hip_bfloat16*)(ws + o_Wtb), ws + o_Wep, ws + o_bpF, ws + o_boF);
    node_pre<<<1024, 256, 0, stream>>>(x, W1, b1, W2, b2, Wp,
                                       ws + o_x2, ws + o_A, ws + o_B);
    hist_kernel<<<6250, 256, 0, stream>>>(ei, (unsigned*)(ws + o_cnt_i));
    scan_blocksum<<<NSCAN_BLOCKS, 256, 0, stream>>>((unsigned*)(ws + o_cnt_i), (unsigned*)(ws + o_bsum));
    scan_top<<<1, 512, 0, stream>>>((unsigned*)(ws + o_bsum), (unsigned*)(ws + o_boff),
                                    (unsigned*)(ws + o_start));
    scan_final<<<NSCAN_BLOCKS, 256, 0, stream>>>((unsigned*)(ws + o_cnt_i), (unsigned*)(ws + o_boff),
                                                 (unsigned*)(ws + o_start));
    scatter_kernel<<<6250, 256, 0, stream>>>(ei, (const unsigned*)(ws + o_start),
                                             (unsigned*)(ws + o_cnt_i), (unsigned*)(ws + o_perm));
    agg_kernel<<<4096, 256, 0, stream>>>(ea, ei, (const unsigned*)(ws + o_perm),
                                         (const unsigned*)(ws + o_start),
                                         ws + o_A, ws + o_B, ws + o_Wep, ws + o_bpF,
                                         ws + o_mean, ws + o_mn, ws + o_mx, ws + o_sd, ws + o_cntf);
    post_kernel<<<6250, 256, 0, stream>>>(ws + o_x2, ws + o_mean, ws + o_mn, ws + o_mx, ws + o_sd,
                                          ws + o_cntf, (const __hip_bfloat16*)(ws + o_Wtb), ws + o_boF,
                                          ws + o_A /*out_pre*/, ws + o_bnsum, ws + o_bnsum2);
    bn_finalize<<<1, 64, 0, stream>>>(ws + o_bnsum, ws + o_bnsum2, gamma, beta,
                                      ws + o_bnscale, ws + o_bnshift);
    bn_pool<<<1563, 256, 0, stream>>>(ws + o_A /*out_pre*/, batch,
                                      ws + o_bnscale, ws + o_bnshift, ws + o_pooled);
    head_kernel<<<1, 256, 0, stream>>>(ws + o_pooled, Wm1, bm1, Wm2, bm2, (float*)d_out);
}

// Round 5
// 966.032 us; speedup vs baseline: 1.2943x; 1.2943x over previous
//
#include <hip/hip_runtime.h>
#include <hip/hip_bf16.h>
#include <math.h>

#define NN 100000
#define NE 1600000
#define FF 64
#define NB 64
#define NSCAN_BLOCKS 391   // ceil(NN/256)

// avg_deg['log'] = sum(log(i+1)*DEG[i]) / sum(DEG)
__device__ __constant__ float AVG_LOG_F = 1.9595436f;

typedef short short8 __attribute__((ext_vector_type(8)));
typedef float f32x4 __attribute__((ext_vector_type(4)));

__device__ __forceinline__ void atomAddF(float* p, float v) {
    __hip_atomic_fetch_add(p, v, __ATOMIC_RELAXED, __HIP_MEMORY_SCOPE_AGENT);
}
__device__ __forceinline__ float bf2f(short v) {
    return __uint_as_float(((unsigned)(unsigned short)v) << 16);
}

// ---------------- fold weights: Wtb = (Wo@Wl)^T in bf16, We'=We@Wp2, biases ----------------
__global__ void fold_weights(const float* __restrict__ Wo, const float* __restrict__ Wl,
                             const float* __restrict__ bo, const float* __restrict__ bl,
                             const float* __restrict__ We, const float* __restrict__ Wp,
                             const float* __restrict__ bp, const float* __restrict__ be,
                             __hip_bfloat16* __restrict__ Wtb,   // [64][832]  Wtb[f][k] = (Wo@Wl)[k][f]
                             float* __restrict__ Wep,  // [16][64]
                             float* __restrict__ bpF, float* __restrict__ boF) {
    int t = blockIdx.x * blockDim.x + threadIdx.x;
    if (t < 832 * 64) {
        int k = t >> 6, f = t & 63;
        float acc = 0.f;
        for (int j = 0; j < 64; j++) acc += Wo[k * 64 + j] * Wl[j * 64 + f];
        Wtb[f * 832 + k] = __float2bfloat16(acc);
    } else if (t < 832 * 64 + 16 * 64) {
        int u = t - 832 * 64; int k = u >> 6, f = u & 63;
        float acc = 0.f;
        for (int j = 0; j < 64; j++) acc += We[k * 64 + j] * Wp[(128 + j) * 64 + f];
        Wep[k * 64 + f] = acc;
    } else if (t < 832 * 64 + 1024 + 64) {
        int f = t - (832 * 64 + 1024);
        float acc = bl[f];
        for (int j = 0; j < 64; j++) acc += bo[j] * Wl[j * 64 + f];
        boF[f] = acc;
    } else if (t < 832 * 64 + 1024 + 128) {
        int f = t - (832 * 64 + 1024 + 64);
        float acc = bp[f];
        for (int j = 0; j < 64; j++) acc += be[j] * Wp[(128 + j) * 64 + f];
        bpF[f] = acc;
    }
}

// ---------------- node pre-MLP + A/B projections (wave per node) ----------------
__global__ __launch_bounds__(256) void node_pre(const float* __restrict__ x,
                                                const float* __restrict__ W1, const float* __restrict__ b1,
                                                const float* __restrict__ W2, const float* __restrict__ b2,
                                                const float* __restrict__ Wp,
                                                float* __restrict__ x2, float* __restrict__ A, float* __restrict__ Bn) {
    __shared__ float W1s[64 * 32], W2s[32 * 64], Wp0s[64 * 64], Wp1s[64 * 64];
    __shared__ float xs[4][64], ts[4][32], x2s[4][64];
    int tid = threadIdx.x;
    for (int i = tid; i < 2048; i += 256) W1s[i] = W1[i];
    for (int i = tid; i < 2048; i += 256) W2s[i] = W2[i];
    for (int i = tid; i < 4096; i += 256) Wp0s[i] = Wp[i];
    for (int i = tid; i < 4096; i += 256) Wp1s[i] = Wp[4096 + i];
    __syncthreads();
    int w = tid >> 6, f = tid & 63;
    int wid = blockIdx.x * 4 + w;
    int nw = gridDim.x * 4;
    for (int v = wid; v < NN; v += nw) {
        xs[w][f] = x[(size_t)v * 64 + f];
        if (f < 32) {
            float tj = b1[f];
            for (int k = 0; k < 64; k++) tj += xs[w][k] * W1s[k * 32 + f];
            ts[w][f] = fmaxf(tj, 0.f);
        }
        float acc2 = b2[f];
        for (int k = 0; k < 32; k++) acc2 += ts[w][k] * W2s[k * 64 + f];
        x2s[w][f] = acc2;
        x2[(size_t)v * 64 + f] = acc2;
        float aa = 0.f, bb = 0.f;
        for (int k = 0; k < 64; k++) {
            float xv = x2s[w][k];
            aa += xv * Wp0s[k * 64 + f];
            bb += xv * Wp1s[k * 64 + f];
        }
        A[(size_t)v * 64 + f] = aa;
        Bn[(size_t)v * 64 + f] = bb;
    }
}

// ---------------- counting sort of edges by dst ----------------
__global__ void hist_kernel(const int* __restrict__ ei, unsigned* __restrict__ cnt_i) {
    int t = blockIdx.x * blockDim.x + threadIdx.x;
    if (t < NE) atomicAdd(&cnt_i[ei[NE + t]], 1u);
}

__global__ void scan_blocksum(const unsigned* __restrict__ cnt_i, unsigned* __restrict__ bsum) {
    __shared__ unsigned red[256];
    int t = blockIdx.x * 256 + threadIdx.x;
    unsigned c = (t < NN) ? cnt_i[t] : 0u;
    red[threadIdx.x] = c; __syncthreads();
    for (int s = 128; s > 0; s >>= 1) {
        if (threadIdx.x < s) red[threadIdx.x] += red[threadIdx.x + s];
        __syncthreads();
    }
    if (threadIdx.x == 0) bsum[blockIdx.x] = red[0];
}

__global__ void scan_top(const unsigned* __restrict__ bsum, unsigned* __restrict__ boff,
                         unsigned* __restrict__ start) {
    __shared__ unsigned sh[512];
    int t = threadIdx.x;
    unsigned v = (t < NSCAN_BLOCKS) ? bsum[t] : 0u;
    sh[t] = v; __syncthreads();
    for (int d = 1; d < 512; d <<= 1) {
        unsigned add = (t >= d) ? sh[t - d] : 0u;
        __syncthreads();
        sh[t] += add;
        __syncthreads();
    }
    if (t < NSCAN_BLOCKS) boff[t] = sh[t] - v;   // exclusive
    if (t == 0) start[NN] = NE;
}

__global__ void scan_final(const unsigned* __restrict__ cnt_i, const unsigned* __restrict__ boff,
                           unsigned* __restrict__ start) {
    __shared__ unsigned sh[256];
    int b = blockIdx.x, t = threadIdx.x;
    int v = b * 256 + t;
    unsigned c = (v < NN) ? cnt_i[v] : 0u;
    sh[t] = c; __syncthreads();
    for (int d = 1; d < 256; d <<= 1) {
        unsigned add = (t >= d) ? sh[t - d] : 0u;
        __syncthreads();
        sh[t] += add;
        __syncthreads();
    }
    if (v < NN) start[v] = boff[b] + sh[t] - c;  // exclusive scan
}

// scatter: materialize sorted edge payloads (src and bf16 edge_attr), no perm
__global__ void scatter_kernel(const int* __restrict__ ei, const float* __restrict__ ea,
                               const unsigned* __restrict__ start,
                               unsigned* __restrict__ cnt_i,
                               __hip_bfloat16* __restrict__ eab, int* __restrict__ src_s) {
    int t = blockIdx.x * blockDim.x + threadIdx.x;
    if (t < NE) {
        int d = ei[NE + t];
        unsigned old = atomicSub(&cnt_i[d], 1u);
        unsigned pos = start[d] + old - 1u;
        src_s[pos] = ei[t];
        const float4* s4 = (const float4*)(ea + (size_t)t * 16);
        float4 a = s4[0], b = s4[1], c = s4[2], e = s4[3];
        short8 o0, o1;
        o0[0] = (short)__bfloat16_as_short(__float2bfloat16(a.x));
        o0[1] = (short)__bfloat16_as_short(__float2bfloat16(a.y));
        o0[2] = (short)__bfloat16_as_short(__float2bfloat16(a.z));
        o0[3] = (short)__bfloat16_as_short(__float2bfloat16(a.w));
        o0[4] = (short)__bfloat16_as_short(__float2bfloat16(b.x));
        o0[5] = (short)__bfloat16_as_short(__float2bfloat16(b.y));
        o0[6] = (short)__bfloat16_as_short(__float2bfloat16(b.z));
        o0[7] = (short)__bfloat16_as_short(__float2bfloat16(b.w));
        o1[0] = (short)__bfloat16_as_short(__float2bfloat16(c.x));
        o1[1] = (short)__bfloat16_as_short(__float2bfloat16(c.y));
        o1[2] = (short)__bfloat16_as_short(__float2bfloat16(c.z));
        o1[3] = (short)__bfloat16_as_short(__float2bfloat16(c.w));
        o1[4] = (short)__bfloat16_as_short(__float2bfloat16(e.x));
        o1[5] = (short)__bfloat16_as_short(__float2bfloat16(e.y));
        o1[6] = (short)__bfloat16_as_short(__float2bfloat16(e.z));
        o1[7] = (short)__bfloat16_as_short(__float2bfloat16(e.w));
        short8* dst8 = (short8*)(eab + (size_t)pos * 16);
        dst8[0] = o0; dst8[1] = o1;
    }
}

// ---------------- fused aggregation + post GEMM (MFMA) + BN stats ----------------
// block = 256 threads = 4 waves = 16 nodes. Wave w aggregates nodes {w, 4+w, 8+w, 12+w}
// sequentially over their sorted edge segments (all reads sequential except Bn gather),
// writes the scaled 832-vector as bf16 straight into LDS, then MFMA vs Wtb.
__global__ __launch_bounds__(256) void agg_post_kernel(const __hip_bfloat16* __restrict__ eab,
                                                       const int* __restrict__ src_s,
                                                       const unsigned* __restrict__ start,
                                                       const float* __restrict__ A, const float* __restrict__ Bn,
                                                       const float* __restrict__ x2,
                                                       const float* __restrict__ Wep, const float* __restrict__ bpF,
                                                       const __hip_bfloat16* __restrict__ Wtb,
                                                       const float* __restrict__ boF,
                                                       float* __restrict__ out_pre,
                                                       float* __restrict__ bnsum, float* __restrict__ bnsum2) {
    __shared__ __hip_bfloat16 As[16 * 840];
    int tid = threadIdx.x, w = tid >> 6, f = tid & 63;
    int base = blockIdx.x * 16;      // 6250 blocks exactly

    float wcol[16];
    #pragma unroll
    for (int k = 0; k < 16; k++) wcol[k] = Wep[k * 64 + f];
    float bpf = bpF[f];

    for (int g = 0; g < 4; ++g) {
        int n = g * 4 + w;
        int v = base + n;
        unsigned s0 = start[v], s1 = start[v + 1];
        int len = (int)(s1 - s0);
        float av = A[(size_t)v * 64 + f] + bpf;
        float s = 0.f, s2 = 0.f, mn = INFINITY, mx = -INFINITY;
        for (unsigned j = s0; j < s1; ++j) {
            int src = src_s[j];
            const short8* ep = (const short8*)(eab + (size_t)j * 16);
            short8 e0 = ep[0], e1 = ep[1];
            float h = av + Bn[(size_t)src * 64 + f];
            #pragma unroll
            for (int k = 0; k < 8; k++) h += bf2f(e0[k]) * wcol[k];
            #pragma unroll
            for (int k = 0; k < 8; k++) h += bf2f(e1[k]) * wcol[8 + k];
            s += h; s2 += h * h;
            mn = fminf(mn, h); mx = fmaxf(mx, h);
        }
        float c = (float)len;
        float d = fmaxf(c, 1.f);
        float inv = 1.f / d;
        float mean = s * inv, mean2 = s2 * inv;
        float sd = sqrtf(fmaxf(mean2 - mean * mean, 0.f) + 1e-5f);
        bool has = len > 0;
        mn = has ? mn : 0.f;
        mx = has ? mx : 0.f;
        float l = __logf(d + 1.f);
        float amp = l * (1.0f / 1.9595436f);
        float iamp = 1.9595436f / l;
        __hip_bfloat16* row = &As[n * 840];
        row[f]        = __float2bfloat16(x2[(size_t)v * 64 + f]);
        row[64 + f]   = __float2bfloat16(mean);
        row[128 + f]  = __float2bfloat16(mn);
        row[192 + f]  = __float2bfloat16(mx);
        row[256 + f]  = __float2bfloat16(sd);
        row[320 + f]  = __float2bfloat16(mean * amp);
        row[384 + f]  = __float2bfloat16(mn * amp);
        row[448 + f]  = __float2bfloat16(mx * amp);
        row[512 + f]  = __float2bfloat16(sd * amp);
        row[576 + f]  = __float2bfloat16(mean * iamp);
        row[640 + f]  = __float2bfloat16(mn * iamp);
        row[704 + f]  = __float2bfloat16(mx * iamp);
        row[768 + f]  = __float2bfloat16(sd * iamp);
    }
    __syncthreads();

    // MFMA phase: lane = m + 16q; A[m][k=q*8+j], B[k][n=m]; D: col=lane&15, row=q*4+reg
    int m = f & 15, q = f >> 4;
    int fbase = w * 16;
    f32x4 acc = {0.f, 0.f, 0.f, 0.f};
    const __hip_bfloat16* arow = &As[m * 840 + q * 8];
    const __hip_bfloat16* brow = &Wtb[(size_t)(fbase + m) * 832 + q * 8];
    #pragma unroll
    for (int s = 0; s < 26; ++s) {
        short8 af = *(const short8*)(arow + s * 32);
        short8 bf = *(const short8*)(brow + s * 32);
        acc = __builtin_amdgcn_mfma_f32_16x16x32_bf16(af, bf, acc, 0, 0, 0);
    }

    float bof = boF[fbase + m];
    float p1 = 0.f, p2 = 0.f;
    #pragma unroll
    for (int r = 0; r < 4; ++r) {
        float vv = acc[r] + bof;
        out_pre[(size_t)(base + q * 4 + r) * 64 + fbase + m] = vv;
        p1 += vv; p2 += vv * vv;
    }
    p1 += __shfl_xor(p1, 16); p2 += __shfl_xor(p2, 16);
    p1 += __shfl_xor(p1, 32); p2 += __shfl_xor(p2, 32);
    if (f < 16) {
        atomAddF(&bnsum[fbase + f], p1);
        atomAddF(&bnsum2[fbase + f], p2);
    }
}

// ---------------- BN finalize ----------------
__global__ void bn_finalize(const float* __restrict__ bnsum, const float* __restrict__ bnsum2,
                            const float* __restrict__ gamma, const float* __restrict__ beta,
                            float* __restrict__ bnscale, float* __restrict__ bnshift) {
    int f = threadIdx.x;
    if (f < 64) {
        float mu = bnsum[f] * (1.0f / NN);
        float var = bnsum2[f] * (1.0f / NN) - mu * mu;
        float sc = gamma[f] / sqrtf(var + 1e-5f);
        bnscale[f] = sc;
        bnshift[f] = beta[f] - mu * sc;
    }
}

// ---------------- BN apply + ReLU + global_add_pool ----------------
__global__ __launch_bounds__(256) void bn_pool(const float* __restrict__ out_pre, const int* __restrict__ batch,
                                               const float* __restrict__ bnscale, const float* __restrict__ bnshift,
                                               float* __restrict__ pooled) {
    __shared__ float red[256];
    int tid = threadIdx.x, f = tid & 63, q = tid >> 6;
    int base = blockIdx.x * 64;
    float sc = bnscale[f], sh = bnshift[f];
    int b_first = batch[base < NN ? base : NN - 1];
    int last = base + 63; if (last >= NN) last = NN - 1;
    int b_last = batch[last];
    if (b_first == b_last) {
        float local = 0.f;
        for (int g = 0; g < 16; ++g) {
            int v = base + g * 4 + q;
            if (v < NN) local += fmaxf(out_pre[(size_t)v * 64 + f] * sc + sh, 0.f);
        }
        red[tid] = local;
        __syncthreads();
        if (tid < 64) atomAddF(&pooled[b_first * 64 + f], red[f] + red[f + 64] + red[f + 128] + red[f + 192]);
    } else {
        for (int g = 0; g < 16; ++g) {
            int v = base + g * 4 + q;
            if (v < NN) {
                float val = fmaxf(out_pre[(size_t)v * 64 + f] * sc + sh, 0.f);
                atomAddF(&pooled[batch[v] * 64 + f], val);
            }
        }
    }
}

// ---------------- head MLP: relu(pooled@Wm1+bm1)@Wm2+bm2 ----------------
__global__ void head_kernel(const float* __restrict__ pooled,
                            const float* __restrict__ Wm1, const float* __restrict__ bm1,
                            const float* __restrict__ Wm2, const float* __restrict__ bm2,
                            float* __restrict__ out) {
    __shared__ float ts[64][104];
    int tid = threadIdx.x;
    for (int t = tid; t < 64 * 100; t += 256) {
        int b = t / 100, j = t % 100;
        float acc = bm1[j];
        for (int k = 0; k < 64; k++) acc += pooled[b * 64 + k] * Wm1[k * 100 + j];
        ts[b][j] = fmaxf(acc, 0.f);
    }
    __syncthreads();
    if (tid < 64) {
        float acc = bm2[0];
        for (int j = 0; j < 100; j++) acc += ts[tid][j] * Wm2[j];
        out[tid] = acc;
    }
}

extern "C" void kernel_launch(void* const* d_in, const int* in_sizes, int n_in,
                              void* d_out, int out_size, void* d_ws, size_t ws_size,
                              hipStream_t stream) {
    const float* x    = (const float*)d_in[0];
    const float* ea   = (const float*)d_in[1];
    const int*   ei   = (const int*)d_in[2];
    const int*   batch= (const int*)d_in[3];
    const float* W1   = (const float*)d_in[4];
    const float* b1   = (const float*)d_in[5];
    const float* W2   = (const float*)d_in[6];
    const float* b2   = (const float*)d_in[7];
    const float* We   = (const float*)d_in[8];
    const float* be   = (const float*)d_in[9];
    const float* Wp   = (const float*)d_in[10];
    const float* bp   = (const float*)d_in[11];
    const float* Wo   = (const float*)d_in[12];
    const float* bo   = (const float*)d_in[13];
    const float* Wl   = (const float*)d_in[14];
    const float* bl   = (const float*)d_in[15];
    const float* gamma= (const float*)d_in[16];
    const float* beta = (const float*)d_in[17];
    const float* Wm1  = (const float*)d_in[18];
    const float* bm1  = (const float*)d_in[19];
    const float* Wm2  = (const float*)d_in[20];
    const float* bm2  = (const float*)d_in[21];

    float* ws = (float*)d_ws;
    constexpr size_t NF = (size_t)NN * 64;              // 6,400,000
    const size_t o_x2     = 0;
    const size_t o_B      = NF;
    const size_t o_A      = 2 * NF;
    const size_t o_outpre = 3 * NF;
    const size_t o_start  = 4 * NF;                     // NN+1 uints
    const size_t o_cnt_i  = o_start + NN + 2;           // NN uints (memset 0)
    const size_t o_bsum   = o_cnt_i + NN;
    const size_t o_boff   = o_bsum + 512;
    const size_t o_eab    = o_boff + 512;               // NE*16 bf16 = NE*8 float slots
    const size_t o_srcs   = o_eab + (size_t)NE * 8;     // NE ints
    const size_t o_Wtb    = o_srcs + NE;                // 64*832 bf16 = 26624 float slots /2
    const size_t o_Wep    = o_Wtb + 64 * 832 / 2;
    const size_t o_bpF    = o_Wep + 16 * 64;
    const size_t o_boF    = o_bpF + 64;
    const size_t o_bnscale= o_boF + 64;
    const size_t o_bnshift= o_bnscale + 64;
    const size_t o_pooled = o_bnshift + 64;             // zero block: pooled + bnsum + bnsum2
    const size_t o_bnsum  = o_pooled + 64 * 64;
    const size_t o_bnsum2 = o_bnsum + 64;

    hipMemsetAsync(ws + o_cnt_i, 0, NN * sizeof(unsigned), stream);
    hipMemsetAsync(ws + o_pooled, 0, (64 * 64 + 128) * sizeof(float), stream);

    fold_weights<<<213, 256, 0, stream>>>(Wo, Wl, bo, bl, We, Wp, bp, be,
                                          (__hip_bfloat16*)(ws + o_Wtb), ws + o_Wep, ws + o_bpF, ws + o_boF);
    node_pre<<<1024, 256, 0, stream>>>(x, W1, b1, W2, b2, Wp,
                                       ws + o_x2, ws + o_A, ws + o_B);
    hist_kernel<<<6250, 256, 0, stream>>>(ei, (unsigned*)(ws + o_cnt_i));
    scan_blocksum<<<NSCAN_BLOCKS, 256, 0, stream>>>((unsigned*)(ws + o_cnt_i), (unsigned*)(ws + o_bsum));
    scan_top<<<1, 512, 0, stream>>>((unsigned*)(ws + o_bsum), (unsigned*)(ws + o_boff),
                                    (unsigned*)(ws + o_start));
    scan_final<<<NSCAN_BLOCKS, 256, 0, stream>>>((unsigned*)(ws + o_cnt_i), (unsigned*)(ws + o_boff),
                                                 (unsigned*)(ws + o_start));
    scatter_kernel<<<6250, 256, 0, stream>>>(ei, ea, (const unsigned*)(ws + o_start),
                                             (unsigned*)(ws + o_cnt_i),
                                             (__hip_bfloat16*)(ws + o_eab), (int*)(ws + o_srcs));
    agg_post_kernel<<<6250, 256, 0, stream>>>((const __hip_bfloat16*)(ws + o_eab),
                                              (const int*)(ws + o_srcs),
                                              (const unsigned*)(ws + o_start),
                                              ws + o_A, ws + o_B, ws + o_x2,
                                              ws + o_Wep, ws + o_bpF,
                                              (const __hip_bfloat16*)(ws + o_Wtb), ws + o_boF,
                                              ws + o_outpre, ws + o_bnsum, ws + o_bnsum2);
    bn_finalize<<<1, 64, 0, stream>>>(ws + o_bnsum, ws + o_bnsum2, gamma, beta,
                                      ws + o_bnscale, ws + o_bnshift);
    bn_pool<<<1563, 256, 0, stream>>>(ws + o_outpre, batch,
                                      ws + o_bnscale, ws + o_bnshift, ws + o_pooled);
    head_kernel<<<1, 256, 0, stream>>>(ws + o_pooled, Wm1, bm1, Wm2, bm2, (float*)d_out);
}

// Round 6
// 921.642 us; speedup vs baseline: 1.3566x; 1.0482x over previous
//
#include <hip/hip_runtime.h>
#include <hip/hip_bf16.h>
#include <math.h>

#define NN 100000
#define NE 1600000
#define FF 64
#define NB 64
#define NSCAN_BLOCKS 391   // ceil(NN/256)

// avg_deg['log'] = sum(log(i+1)*DEG[i]) / sum(DEG)
__device__ __constant__ float AVG_LOG_F = 1.9595436f;

typedef short short8 __attribute__((ext_vector_type(8)));
typedef float f32x4 __attribute__((ext_vector_type(4)));

__device__ __forceinline__ void atomAddF(float* p, float v) {
    __hip_atomic_fetch_add(p, v, __ATOMIC_RELAXED, __HIP_MEMORY_SCOPE_AGENT);
}
__device__ __forceinline__ float bf2f(short v) {
    return __uint_as_float(((unsigned)(unsigned short)v) << 16);
}

// ---------------- fold weights: Wtb = (Wo@Wl)^T in bf16, We'=We@Wp2, biases ----------------
__global__ void fold_weights(const float* __restrict__ Wo, const float* __restrict__ Wl,
                             const float* __restrict__ bo, const float* __restrict__ bl,
                             const float* __restrict__ We, const float* __restrict__ Wp,
                             const float* __restrict__ bp, const float* __restrict__ be,
                             __hip_bfloat16* __restrict__ Wtb,   // [64][832]  Wtb[f][k] = (Wo@Wl)[k][f]
                             float* __restrict__ Wep,  // [16][64]
                             float* __restrict__ bpF, float* __restrict__ boF) {
    int t = blockIdx.x * blockDim.x + threadIdx.x;
    if (t < 832 * 64) {
        int k = t >> 6, f = t & 63;
        float acc = 0.f;
        for (int j = 0; j < 64; j++) acc += Wo[k * 64 + j] * Wl[j * 64 + f];
        Wtb[f * 832 + k] = __float2bfloat16(acc);
    } else if (t < 832 * 64 + 16 * 64) {
        int u = t - 832 * 64; int k = u >> 6, f = u & 63;
        float acc = 0.f;
        for (int j = 0; j < 64; j++) acc += We[k * 64 + j] * Wp[(128 + j) * 64 + f];
        Wep[k * 64 + f] = acc;
    } else if (t < 832 * 64 + 1024 + 64) {
        int f = t - (832 * 64 + 1024);
        float acc = bl[f];
        for (int j = 0; j < 64; j++) acc += bo[j] * Wl[j * 64 + f];
        boF[f] = acc;
    } else if (t < 832 * 64 + 1024 + 128) {
        int f = t - (832 * 64 + 1024 + 64);
        float acc = bp[f];
        for (int j = 0; j < 64; j++) acc += be[j] * Wp[(128 + j) * 64 + f];
        bpF[f] = acc;
    }
}

// ---------------- node pre-MLP + A/B projections (wave per node); Bn stored bf16 ----------------
__global__ __launch_bounds__(256) void node_pre(const float* __restrict__ x,
                                                const float* __restrict__ W1, const float* __restrict__ b1,
                                                const float* __restrict__ W2, const float* __restrict__ b2,
                                                const float* __restrict__ Wp,
                                                float* __restrict__ x2, float* __restrict__ A,
                                                __hip_bfloat16* __restrict__ Bnb) {
    __shared__ float W1s[64 * 32], W2s[32 * 64], Wp0s[64 * 64], Wp1s[64 * 64];
    __shared__ float xs[4][64], ts[4][32], x2s[4][64];
    int tid = threadIdx.x;
    for (int i = tid; i < 2048; i += 256) W1s[i] = W1[i];
    for (int i = tid; i < 2048; i += 256) W2s[i] = W2[i];
    for (int i = tid; i < 4096; i += 256) Wp0s[i] = Wp[i];
    for (int i = tid; i < 4096; i += 256) Wp1s[i] = Wp[4096 + i];
    __syncthreads();
    int w = tid >> 6, f = tid & 63;
    int wid = blockIdx.x * 4 + w;
    int nw = gridDim.x * 4;
    for (int v = wid; v < NN; v += nw) {
        xs[w][f] = x[(size_t)v * 64 + f];
        if (f < 32) {
            float tj = b1[f];
            for (int k = 0; k < 64; k++) tj += xs[w][k] * W1s[k * 32 + f];
            ts[w][f] = fmaxf(tj, 0.f);
        }
        float acc2 = b2[f];
        for (int k = 0; k < 32; k++) acc2 += ts[w][k] * W2s[k * 64 + f];
        x2s[w][f] = acc2;
        x2[(size_t)v * 64 + f] = acc2;
        float aa = 0.f, bb = 0.f;
        for (int k = 0; k < 64; k++) {
            float xv = x2s[w][k];
            aa += xv * Wp0s[k * 64 + f];
            bb += xv * Wp1s[k * 64 + f];
        }
        A[(size_t)v * 64 + f] = aa;
        Bnb[(size_t)v * 64 + f] = __float2bfloat16(bb);
    }
}

// ---------------- counting sort of edges by dst ----------------
__global__ void hist_kernel(const int* __restrict__ ei, unsigned* __restrict__ cnt_i) {
    int t = blockIdx.x * blockDim.x + threadIdx.x;
    if (t < NE) atomicAdd(&cnt_i[ei[NE + t]], 1u);
}

__global__ void scan_blocksum(const unsigned* __restrict__ cnt_i, unsigned* __restrict__ bsum) {
    __shared__ unsigned red[256];
    int t = blockIdx.x * 256 + threadIdx.x;
    unsigned c = (t < NN) ? cnt_i[t] : 0u;
    red[threadIdx.x] = c; __syncthreads();
    for (int s = 128; s > 0; s >>= 1) {
        if (threadIdx.x < s) red[threadIdx.x] += red[threadIdx.x + s];
        __syncthreads();
    }
    if (threadIdx.x == 0) bsum[blockIdx.x] = red[0];
}

__global__ void scan_top(const unsigned* __restrict__ bsum, unsigned* __restrict__ boff,
                         unsigned* __restrict__ start) {
    __shared__ unsigned sh[512];
    int t = threadIdx.x;
    unsigned v = (t < NSCAN_BLOCKS) ? bsum[t] : 0u;
    sh[t] = v; __syncthreads();
    for (int d = 1; d < 512; d <<= 1) {
        unsigned add = (t >= d) ? sh[t - d] : 0u;
        __syncthreads();
        sh[t] += add;
        __syncthreads();
    }
    if (t < NSCAN_BLOCKS) boff[t] = sh[t] - v;   // exclusive
    if (t == 0) start[NN] = NE;
}

__global__ void scan_final(const unsigned* __restrict__ cnt_i, const unsigned* __restrict__ boff,
                           unsigned* __restrict__ start) {
    __shared__ unsigned sh[256];
    int b = blockIdx.x, t = threadIdx.x;
    int v = b * 256 + t;
    unsigned c = (v < NN) ? cnt_i[v] : 0u;
    sh[t] = c; __syncthreads();
    for (int d = 1; d < 256; d <<= 1) {
        unsigned add = (t >= d) ? sh[t - d] : 0u;
        __syncthreads();
        sh[t] += add;
        __syncthreads();
    }
    if (v < NN) start[v] = boff[b] + sh[t] - c;  // exclusive scan
}

// scatter: materialize sorted edge payloads (src and bf16 edge_attr); pads element NE
__global__ void scatter_kernel(const int* __restrict__ ei, const float* __restrict__ ea,
                               const unsigned* __restrict__ start,
                               unsigned* __restrict__ cnt_i,
                               __hip_bfloat16* __restrict__ eab, int* __restrict__ src_s) {
    int t = blockIdx.x * blockDim.x + threadIdx.x;
    if (t == 0) {
        // pad slot NE: safe target for clamped prefetches of zero-degree tail nodes
        src_s[NE] = 0;
        short8 z = {0, 0, 0, 0, 0, 0, 0, 0};
        short8* p = (short8*)(eab + (size_t)NE * 16);
        p[0] = z; p[1] = z;
    }
    if (t < NE) {
        int d = ei[NE + t];
        unsigned old = atomicSub(&cnt_i[d], 1u);
        unsigned pos = start[d] + old - 1u;
        src_s[pos] = ei[t];
        const float4* s4 = (const float4*)(ea + (size_t)t * 16);
        float4 a = s4[0], b = s4[1], c = s4[2], e = s4[3];
        short8 o0, o1;
        o0[0] = (short)__bfloat16_as_short(__float2bfloat16(a.x));
        o0[1] = (short)__bfloat16_as_short(__float2bfloat16(a.y));
        o0[2] = (short)__bfloat16_as_short(__float2bfloat16(a.z));
        o0[3] = (short)__bfloat16_as_short(__float2bfloat16(a.w));
        o0[4] = (short)__bfloat16_as_short(__float2bfloat16(b.x));
        o0[5] = (short)__bfloat16_as_short(__float2bfloat16(b.y));
        o0[6] = (short)__bfloat16_as_short(__float2bfloat16(b.z));
        o0[7] = (short)__bfloat16_as_short(__float2bfloat16(b.w));
        o1[0] = (short)__bfloat16_as_short(__float2bfloat16(c.x));
        o1[1] = (short)__bfloat16_as_short(__float2bfloat16(c.y));
        o1[2] = (short)__bfloat16_as_short(__float2bfloat16(c.z));
        o1[3] = (short)__bfloat16_as_short(__float2bfloat16(c.w));
        o1[4] = (short)__bfloat16_as_short(__float2bfloat16(e.x));
        o1[5] = (short)__bfloat16_as_short(__float2bfloat16(e.y));
        o1[6] = (short)__bfloat16_as_short(__float2bfloat16(e.z));
        o1[7] = (short)__bfloat16_as_short(__float2bfloat16(e.w));
        short8* dst8 = (short8*)(eab + (size_t)pos * 16);
        dst8[0] = o0; dst8[1] = o1;
    }
}

// ---------------- fused aggregation + post GEMM (MFMA) + BN stats ----------------
// block = 256 threads = 4 waves = 16 nodes. Wave w processes its 4 node-segments
// INTERLEAVED in one j-loop: load phase (4 src_s + 4 eab, clamped, unconditional),
// then 4 independent Bnb gathers, then predicated compute -> 4x memory-level
// parallelism on the gather chain. Then bf16 LDS A-tile + MFMA vs Wtb.
__global__ __launch_bounds__(256) void agg_post_kernel(const __hip_bfloat16* __restrict__ eab,
                                                       const int* __restrict__ src_s,
                                                       const unsigned* __restrict__ start,
                                                       const float* __restrict__ A,
                                                       const unsigned short* __restrict__ Bnb,
                                                       const float* __restrict__ x2,
                                                       const float* __restrict__ Wep, const float* __restrict__ bpF,
                                                       const __hip_bfloat16* __restrict__ Wtb,
                                                       const float* __restrict__ boF,
                                                       float* __restrict__ out_pre,
                                                       float* __restrict__ bnsum, float* __restrict__ bnsum2) {
    __shared__ __hip_bfloat16 As[16 * 840];
    int tid = threadIdx.x, w = tid >> 6, f = tid & 63;
    int base = blockIdx.x * 16;      // 6250 blocks exactly

    float wcol[16];
    #pragma unroll
    for (int k = 0; k < 16; k++) wcol[k] = Wep[k * 64 + f];
    float bpf = bpF[f];

    unsigned s0[4]; int len[4], lim[4]; float av[4];
    float sA[4] = {0.f, 0.f, 0.f, 0.f}, s2A[4] = {0.f, 0.f, 0.f, 0.f};
    float mnA[4], mxA[4];
    int maxlen = 0;
    #pragma unroll
    for (int g = 0; g < 4; ++g) {
        int v = base + g * 4 + w;
        unsigned a = start[v], b = start[v + 1];
        s0[g] = a; len[g] = (int)(b - a);
        lim[g] = len[g] > 0 ? len[g] - 1 : 0;
        maxlen = max(maxlen, len[g]);
        av[g] = A[(size_t)v * 64 + f] + bpf;
        mnA[g] = INFINITY; mxA[g] = -INFINITY;
    }

    for (int j = 0; j < maxlen; ++j) {
        int src[4]; short8 e0[4], e1[4];
        #pragma unroll
        for (int g = 0; g < 4; ++g) {
            unsigned idx = s0[g] + (unsigned)min(j, lim[g]);
            src[g] = src_s[idx];
            const short8* ep = (const short8*)(eab + (size_t)idx * 16);
            e0[g] = ep[0]; e1[g] = ep[1];
        }
        float bn[4];
        #pragma unroll
        for (int g = 0; g < 4; ++g)
            bn[g] = bf2f((short)Bnb[(size_t)src[g] * 64 + f]);
        #pragma unroll
        for (int g = 0; g < 4; ++g) {
            float h = av[g] + bn[g];
            #pragma unroll
            for (int k = 0; k < 8; k++) h += bf2f(e0[g][k]) * wcol[k];
            #pragma unroll
            for (int k = 0; k < 8; k++) h += bf2f(e1[g][k]) * wcol[8 + k];
            bool valid = j < len[g];
            float hm = valid ? h : 0.f;
            sA[g] += hm; s2A[g] += hm * hm;
            mnA[g] = fminf(mnA[g], valid ? h : INFINITY);
            mxA[g] = fmaxf(mxA[g], valid ? h : -INFINITY);
        }
    }

    #pragma unroll
    for (int g = 0; g < 4; ++g) {
        int n = g * 4 + w;
        int v = base + n;
        float c = (float)len[g];
        float d = fmaxf(c, 1.f);
        float inv = 1.f / d;
        float mean = sA[g] * inv, mean2 = s2A[g] * inv;
        float sd = sqrtf(fmaxf(mean2 - mean * mean, 0.f) + 1e-5f);
        bool has = len[g] > 0;
        float mn = has ? mnA[g] : 0.f;
        float mx = has ? mxA[g] : 0.f;
        float l = __logf(d + 1.f);
        float amp = l * (1.0f / 1.9595436f);
        float iamp = 1.9595436f / l;
        __hip_bfloat16* row = &As[n * 840];
        row[f]        = __float2bfloat16(x2[(size_t)v * 64 + f]);
        row[64 + f]   = __float2bfloat16(mean);
        row[128 + f]  = __float2bfloat16(mn);
        row[192 + f]  = __float2bfloat16(mx);
        row[256 + f]  = __float2bfloat16(sd);
        row[320 + f]  = __float2bfloat16(mean * amp);
        row[384 + f]  = __float2bfloat16(mn * amp);
        row[448 + f]  = __float2bfloat16(mx * amp);
        row[512 + f]  = __float2bfloat16(sd * amp);
        row[576 + f]  = __float2bfloat16(mean * iamp);
        row[640 + f]  = __float2bfloat16(mn * iamp);
        row[704 + f]  = __float2bfloat16(mx * iamp);
        row[768 + f]  = __float2bfloat16(sd * iamp);
    }
    __syncthreads();

    // MFMA phase: lane = m + 16q; A[m][k=q*8+j], B[k][n=m]; D: col=lane&15, row=q*4+reg
    int m = f & 15, q = f >> 4;
    int fbase = w * 16;
    f32x4 acc = {0.f, 0.f, 0.f, 0.f};
    const __hip_bfloat16* arow = &As[m * 840 + q * 8];
    const __hip_bfloat16* brow = &Wtb[(size_t)(fbase + m) * 832 + q * 8];
    #pragma unroll
    for (int s = 0; s < 26; ++s) {
        short8 af = *(const short8*)(arow + s * 32);
        short8 bf = *(const short8*)(brow + s * 32);
        acc = __builtin_amdgcn_mfma_f32_16x16x32_bf16(af, bf, acc, 0, 0, 0);
    }

    float bof = boF[fbase + m];
    float p1 = 0.f, p2 = 0.f;
    #pragma unroll
    for (int r = 0; r < 4; ++r) {
        float vv = acc[r] + bof;
        out_pre[(size_t)(base + q * 4 + r) * 64 + fbase + m] = vv;
        p1 += vv; p2 += vv * vv;
    }
    p1 += __shfl_xor(p1, 16); p2 += __shfl_xor(p2, 16);
    p1 += __shfl_xor(p1, 32); p2 += __shfl_xor(p2, 32);
    if (f < 16) {
        atomAddF(&bnsum[fbase + f], p1);
        atomAddF(&bnsum2[fbase + f], p2);
    }
}

// ---------------- BN finalize ----------------
__global__ void bn_finalize(const float* __restrict__ bnsum, const float* __restrict__ bnsum2,
                            const float* __restrict__ gamma, const float* __restrict__ beta,
                            float* __restrict__ bnscale, float* __restrict__ bnshift) {
    int f = threadIdx.x;
    if (f < 64) {
        float mu = bnsum[f] * (1.0f / NN);
        float var = bnsum2[f] * (1.0f / NN) - mu * mu;
        float sc = gamma[f] / sqrtf(var + 1e-5f);
        bnscale[f] = sc;
        bnshift[f] = beta[f] - mu * sc;
    }
}

// ---------------- BN apply + ReLU + global_add_pool ----------------
__global__ __launch_bounds__(256) void bn_pool(const float* __restrict__ out_pre, const int* __restrict__ batch,
                                               const float* __restrict__ bnscale, const float* __restrict__ bnshift,
                                               float* __restrict__ pooled) {
    __shared__ float red[256];
    int tid = threadIdx.x, f = tid & 63, q = tid >> 6;
    int base = blockIdx.x * 64;
    float sc = bnscale[f], sh = bnshift[f];
    int b_first = batch[base < NN ? base : NN - 1];
    int last = base + 63; if (last >= NN) last = NN - 1;
    int b_last = batch[last];
    if (b_first == b_last) {
        float local = 0.f;
        for (int g = 0; g < 16; ++g) {
            int v = base + g * 4 + q;
            if (v < NN) local += fmaxf(out_pre[(size_t)v * 64 + f] * sc + sh, 0.f);
        }
        red[tid] = local;
        __syncthreads();
        if (tid < 64) atomAddF(&pooled[b_first * 64 + f], red[f] + red[f + 64] + red[f + 128] + red[f + 192]);
    } else {
        for (int g = 0; g < 16; ++g) {
            int v = base + g * 4 + q;
            if (v < NN) {
                float val = fmaxf(out_pre[(size_t)v * 64 + f] * sc + sh, 0.f);
                atomAddF(&pooled[batch[v] * 64 + f], val);
            }
        }
    }
}

// ---------------- head MLP: relu(pooled@Wm1+bm1)@Wm2+bm2 ----------------
__global__ void head_kernel(const float* __restrict__ pooled,
                            const float* __restrict__ Wm1, const float* __restrict__ bm1,
                            const float* __restrict__ Wm2, const float* __restrict__ bm2,
                            float* __restrict__ out) {
    __shared__ float ts[64][104];
    int tid = threadIdx.x;
    for (int t = tid; t < 64 * 100; t += 256) {
        int b = t / 100, j = t % 100;
        float acc = bm1[j];
        for (int k = 0; k < 64; k++) acc += pooled[b * 64 + k] * Wm1[k * 100 + j];
        ts[b][j] = fmaxf(acc, 0.f);
    }
    __syncthreads();
    if (tid < 64) {
        float acc = bm2[0];
        for (int j = 0; j < 100; j++) acc += ts[tid][j] * Wm2[j];
        out[tid] = acc;
    }
}

extern "C" void kernel_launch(void* const* d_in, const int* in_sizes, int n_in,
                              void* d_out, int out_size, void* d_ws, size_t ws_size,
                              hipStream_t stream) {
    const float* x    = (const float*)d_in[0];
    const float* ea   = (const float*)d_in[1];
    const int*   ei   = (const int*)d_in[2];
    const int*   batch= (const int*)d_in[3];
    const float* W1   = (const float*)d_in[4];
    const float* b1   = (const float*)d_in[5];
    const float* W2   = (const float*)d_in[6];
    const float* b2   = (const float*)d_in[7];
    const float* We   = (const float*)d_in[8];
    const float* be   = (const float*)d_in[9];
    const float* Wp   = (const float*)d_in[10];
    const float* bp   = (const float*)d_in[11];
    const float* Wo   = (const float*)d_in[12];
    const float* bo   = (const float*)d_in[13];
    const float* Wl   = (const float*)d_in[14];
    const float* bl   = (const float*)d_in[15];
    const float* gamma= (const float*)d_in[16];
    const float* beta = (const float*)d_in[17];
    const float* Wm1  = (const float*)d_in[18];
    const float* bm1  = (const float*)d_in[19];
    const float* Wm2  = (const float*)d_in[20];
    const float* bm2  = (const float*)d_in[21];

    float* ws = (float*)d_ws;
    constexpr size_t NF = (size_t)NN * 64;              // 6,400,000
    const size_t o_x2     = 0;
    const size_t o_B      = NF;                         // Bnb bf16 (NF ushorts, NF/2 float slots used)
    const size_t o_A      = 2 * NF;
    const size_t o_outpre = 3 * NF;
    const size_t o_start  = 4 * NF;                     // NN+1 uints
    const size_t o_cnt_i  = o_start + NN + 2;           // NN uints (memset 0)
    const size_t o_bsum   = o_cnt_i + NN;
    const size_t o_boff   = o_bsum + 512;
    const size_t o_eab    = o_boff + 512;               // (NE+1)*16 bf16 = (NE+1)*8 float slots
    const size_t o_srcs   = o_eab + (size_t)(NE + 1) * 8;  // NE+1 ints
    const size_t o_Wtb    = o_srcs + NE + 2;
    const size_t o_Wep    = o_Wtb + 64 * 832 / 2;
    const size_t o_bpF    = o_Wep + 16 * 64;
    const size_t o_boF    = o_bpF + 64;
    const size_t o_bnscale= o_boF + 64;
    const size_t o_bnshift= o_bnscale + 64;
    const size_t o_pooled = o_bnshift + 64;             // zero block: pooled + bnsum + bnsum2
    const size_t o_bnsum  = o_pooled + 64 * 64;
    const size_t o_bnsum2 = o_bnsum + 64;

    hipMemsetAsync(ws + o_cnt_i, 0, NN * sizeof(unsigned), stream);
    hipMemsetAsync(ws + o_pooled, 0, (64 * 64 + 128) * sizeof(float), stream);

    fold_weights<<<213, 256, 0, stream>>>(Wo, Wl, bo, bl, We, Wp, bp, be,
                                          (__hip_bfloat16*)(ws + o_Wtb), ws + o_Wep, ws + o_bpF, ws + o_boF);
    node_pre<<<1024, 256, 0, stream>>>(x, W1, b1, W2, b2, Wp,
                                       ws + o_x2, ws + o_A, (__hip_bfloat16*)(ws + o_B));
    hist_kernel<<<6250, 256, 0, stream>>>(ei, (unsigned*)(ws + o_cnt_i));
    scan_blocksum<<<NSCAN_BLOCKS, 256, 0, stream>>>((unsigned*)(ws + o_cnt_i), (unsigned*)(ws + o_bsum));
    scan_top<<<1, 512, 0, stream>>>((unsigned*)(ws + o_bsum), (unsigned*)(ws + o_boff),
                                    (unsigned*)(ws + o_start));
    scan_final<<<NSCAN_BLOCKS, 256, 0, stream>>>((unsigned*)(ws + o_cnt_i), (unsigned*)(ws + o_boff),
                                                 (unsigned*)(ws + o_start));
    scatter_kernel<<<6250, 256, 0, stream>>>(ei, ea, (const unsigned*)(ws + o_start),
                                             (unsigned*)(ws + o_cnt_i),
                                             (__hip_bfloat16*)(ws + o_eab), (int*)(ws + o_srcs));
    agg_post_kernel<<<6250, 256, 0, stream>>>((const __hip_bfloat16*)(ws + o_eab),
                                              (const int*)(ws + o_srcs),
                                              (const unsigned*)(ws + o_start),
                                              ws + o_A, (const unsigned short*)(ws + o_B), ws + o_x2,
                                              ws + o_Wep, ws + o_bpF,
                                              (const __hip_bfloat16*)(ws + o_Wtb), ws + o_boF,
                                              ws + o_outpre, ws + o_bnsum, ws + o_bnsum2);
    bn_finalize<<<1, 64, 0, stream>>>(ws + o_bnsum, ws + o_bnsum2, gamma, beta,
                                      ws + o_bnscale, ws + o_bnshift);
    bn_pool<<<1563, 256, 0, stream>>>(ws + o_outpre, batch,
                                      ws + o_bnscale, ws + o_bnshift, ws + o_pooled);
    head_kernel<<<1, 256, 0, stream>>>(ws + o_pooled, Wm1, bm1, Wm2, bm2, (float*)d_out);
}